// Round 2
// baseline (581.098 us; speedup 1.0000x reference)
//
#include <hip/hip_runtime.h>

#define B 8
#define N 2048
#define KF 256
#define DF 64
#define LOG2E 1.44269504088896340736f
#define IC 8
#define ICH (N / IC)   // 256

__device__ __forceinline__ float lrelu(float x) { return fmaxf(x, 0.2f * x); }
__device__ __forceinline__ float eluf(float x) { return x > 0.f ? x : expm1f(x); }

// ---- A: Wh = h @ W, fused f1/f2. W staged in LDS; h rows read as
// wave-uniform scalars (no tid in address -> s_load). 16 rows/block. ----
__global__ __launch_bounds__(256) void k_wh(const float* __restrict__ h,
                                            const float* __restrict__ W,
                                            const float* __restrict__ a,
                                            float* __restrict__ Wh,
                                            float* __restrict__ f1,
                                            float* __restrict__ f2) {
    __shared__ float lw[KF * DF];   // 64 KB
    int t = threadIdx.x;
    int lane = t & 63, wv = t >> 6;
    long rowbase = (long)blockIdx.x * 16;

    const float4* W4 = (const float4*)W;
    float4* lw4 = (float4*)lw;
    for (int idx = t; idx < KF * DF / 4; idx += 256) lw4[idx] = W4[idx];
    __syncthreads();

    long r0 = rowbase + wv * 4;
    const float* hrow = h + r0 * KF;
    float acc[4] = {0.f, 0.f, 0.f, 0.f};
    #pragma unroll 32
    for (int k = 0; k < KF; k++) {
        float wk = lw[k * DF + lane];
        #pragma unroll
        for (int r = 0; r < 4; r++)
            acc[r] = fmaf(hrow[r * KF + k], wk, acc[r]);   // uniform addr
    }

    float a1 = a[lane], a2 = a[DF + lane];
    #pragma unroll
    for (int r = 0; r < 4; r++) {
        Wh[(r0 + r) * DF + lane] = acc[r];
        float s1 = acc[r] * a1;
        float s2 = acc[r] * a2;
        #pragma unroll
        for (int off = 32; off; off >>= 1) {
            s1 += __shfl_xor(s1, off, 64);
            s2 += __shfl_xor(s2, off, 64);
        }
        if (lane == 0) { f1[r0 + r] = s1; f2[r0 + r] = s2; }
    }
}

// ---- per-batch max of f1 (8 blocks, tree reduce, no atomics) ----
__global__ __launch_bounds__(256) void k_colmax(const float* __restrict__ f1,
                                                float* __restrict__ f1max) {
    __shared__ float red[256];
    int t = threadIdx.x, b = blockIdx.x;
    float m = -1e30f;
    #pragma unroll
    for (int k = 0; k < N / 256; k++) m = fmaxf(m, f1[b * N + k * 256 + t]);
    red[t] = m;
    __syncthreads();
    for (int s = 128; s; s >>= 1) {
        if (t < s) red[t] = fmaxf(red[t], red[t + s]);
        __syncthreads();
    }
    if (t == 0) f1max[b] = red[0];
}

// ---- D: partial denom slabs (no atomics): dpart[ic][b*N+j] ----
__global__ __launch_bounds__(256) void k_denom(const float* __restrict__ f1,
                                               const float* __restrict__ f2,
                                               const float* __restrict__ f1max,
                                               float* __restrict__ dpart) {
    __shared__ float lf1[ICH];
    int t = threadIdx.x;
    int b = blockIdx.z, ic = blockIdx.y;
    int j = blockIdx.x * 256 + t;
    lf1[t] = f1[b * N + ic * ICH + t];
    __syncthreads();
    float f2j = f2[b * N + j];
    float mL = lrelu(f1max[b] + f2j) * LOG2E;
    float s = 0.f;
    for (int ii = 0; ii < ICH; ii++) {
        float l = lrelu(lf1[ii] + f2j);
        s += exp2f(fmaf(l, LOG2E, -mL));
    }
    dpart[((long)ic * B + b) * N + j] = s;
}

// ---- pack per-j constants: {f2, m*LOG2E, 1/denom, 0} ----
__global__ void k_pack(const float* __restrict__ f2,
                       const float* __restrict__ dpart,
                       const float* __restrict__ f1max,
                       float4* __restrict__ col) {
    int idx = blockIdx.x * 256 + threadIdx.x;   // 16384
    int b = idx >> 11;
    float d = 0.f;
    #pragma unroll
    for (int ic = 0; ic < IC; ic++) d += dpart[((long)ic * B + b) * N + (idx & (N - 1))];
    float f2j = f2[idx];
    float mL = lrelu(f1max[b] + f2j) * LOG2E;
    col[idx] = make_float4(f2j, mL, 1.0f / d, 0.f);
}

// ---- E: main contraction. 2 threads/row x 32 feats; j chunked by NC. ----
template <int NC, bool DIRECT>
__global__ __launch_bounds__(256) void k_main(const float* __restrict__ Wh,
                                              const float* __restrict__ f1,
                                              const float4* __restrict__ col,
                                              float* __restrict__ outp) {
    int t = threadIdx.x;
    int i2 = t >> 1, qq = t & 1;
    int c = blockIdx.x, iblk = blockIdx.y, b = blockIdx.z;
    long row = (long)b * N + (long)iblk * 128 + i2;
    float f1i = f1[row];
    float4 acc[8];
    #pragma unroll
    for (int q = 0; q < 8; q++) acc[q] = make_float4(0.f, 0.f, 0.f, 0.f);

    const int CH = N / NC;
    long jbase = (long)b * N + (long)c * CH;
    const float4* wh4 = (const float4*)Wh + jbase * 16 + qq * 8;

    for (int jj = 0; jj < CH; jj++) {
        float4 cv = col[jbase + jj];                  // wave-uniform -> s_load
        float t0 = f1i + cv.x;
        float l = fmaxf(t0, 0.2f * t0);
        float w = exp2f(fmaf(l, LOG2E, -cv.y)) * cv.z;
        const float4* wr = wh4 + (long)jj * 16;
        #pragma unroll
        for (int q = 0; q < 8; q++) {
            float4 v = wr[q];
            acc[q].x = fmaf(w, v.x, acc[q].x);
            acc[q].y = fmaf(w, v.y, acc[q].y);
            acc[q].z = fmaf(w, v.z, acc[q].z);
            acc[q].w = fmaf(w, v.w, acc[q].w);
        }
    }

    if (DIRECT) {
        float4* o4 = (float4*)outp + row * 16 + qq * 8;
        #pragma unroll
        for (int q = 0; q < 8; q++) {
            float4 v = acc[q];
            v.x = eluf(v.x); v.y = eluf(v.y); v.z = eluf(v.z); v.w = eluf(v.w);
            o4[q] = v;
        }
    } else {
        float4* p4 = (float4*)outp + ((long)c * (B * N) + row) * 16 + qq * 8;
        #pragma unroll
        for (int q = 0; q < 8; q++) p4[q] = acc[q];
    }
}

// ---- F: reduce NC partials + ELU ----
template <int NC>
__global__ void k_reduce(const float4* __restrict__ part, float4* __restrict__ out) {
    long idx = (long)blockIdx.x * 256 + threadIdx.x;   // 262144 float4s
    const long stride = (long)B * N * 16;
    float4 s = part[idx];
    #pragma unroll
    for (int c = 1; c < NC; c++) {
        float4 v = part[(long)c * stride + idx];
        s.x += v.x; s.y += v.y; s.z += v.z; s.w += v.w;
    }
    s.x = eluf(s.x); s.y = eluf(s.y); s.z = eluf(s.z); s.w = eluf(s.w);
    out[idx] = s;
}

extern "C" void kernel_launch(void* const* d_in, const int* in_sizes, int n_in,
                              void* d_out, int out_size, void* d_ws, size_t ws_size,
                              hipStream_t stream) {
    const float* h = (const float*)d_in[0];
    const float* W = (const float*)d_in[1];
    const float* a = (const float*)d_in[2];
    float* out = (float*)d_out;

    char* ws = (char*)d_ws;
    const size_t NB = (size_t)B * N;          // 16384 rows
    size_t off = 0;
    float* Wh    = (float*)(ws + off); off += NB * DF * sizeof(float);     // 4 MB
    float* f1    = (float*)(ws + off); off += NB * sizeof(float);
    float* f2    = (float*)(ws + off); off += NB * sizeof(float);
    float* dpart = (float*)(ws + off); off += (size_t)IC * NB * sizeof(float); // 512 KB
    float4* col  = (float4*)(ws + off); off += NB * sizeof(float4);
    float* f1max = (float*)(ws + off); off += 64;
    off = (off + 255) & ~(size_t)255;
    float* part  = (float*)(ws + off);
    const size_t chunk_bytes = NB * DF * sizeof(float);                    // 4 MB

    int NC = 1;
    if (off + 8 * chunk_bytes <= ws_size) NC = 8;
    else if (off + 4 * chunk_bytes <= ws_size) NC = 4;
    else if (off + 2 * chunk_bytes <= ws_size) NC = 2;

    k_wh<<<NB / 16, 256, 0, stream>>>(h, W, a, Wh, f1, f2);
    k_colmax<<<B, 256, 0, stream>>>(f1, f1max);
    k_denom<<<dim3(N / 256, IC, B), 256, 0, stream>>>(f1, f2, f1max, dpart);
    k_pack<<<NB / 256, 256, 0, stream>>>(f2, dpart, f1max, col);

    if (NC == 8) {
        k_main<8, false><<<dim3(8, N / 128, B), 256, 0, stream>>>(Wh, f1, col, part);
        k_reduce<8><<<(NB * DF / 4) / 256, 256, 0, stream>>>((const float4*)part, (float4*)out);
    } else if (NC == 4) {
        k_main<4, false><<<dim3(4, N / 128, B), 256, 0, stream>>>(Wh, f1, col, part);
        k_reduce<4><<<(NB * DF / 4) / 256, 256, 0, stream>>>((const float4*)part, (float4*)out);
    } else if (NC == 2) {
        k_main<2, false><<<dim3(2, N / 128, B), 256, 0, stream>>>(Wh, f1, col, part);
        k_reduce<2><<<(NB * DF / 4) / 256, 256, 0, stream>>>((const float4*)part, (float4*)out);
    } else {
        k_main<1, true><<<dim3(1, N / 128, B), 256, 0, stream>>>(Wh, f1, col, out);
    }
}